// Round 1
// baseline (347.752 us; speedup 1.0000x reference)
//
#include <hip/hip_runtime.h>

// x: (B=64, NUM_UNITS=32, IN_CH=256, UNIT=128) fp32, contiguous.
// Reference reshape is a memory reinterpret:
//   u_hat[b, i, n, u] = x_flat[b*1048576 + i*4096 + n*128 + u]
// s[b,n,u] = (1/256) * sum_i u_hat[b,i,n,u];  out = squash(s) over u (128).
// Output: (B, NUM_UNITS, UNIT, 1) = 64*32*128 fp32.

#define BATCH     64
#define NUM_UNITS 32
#define IN_CH     256
#define UNIT      128

__global__ __launch_bounds__(256) void capsule_squash_kernel(
    const float* __restrict__ x, float* __restrict__ out)
{
    const int blk = blockIdx.x;      // 0..2047  == b*32 + n
    const int b   = blk >> 5;
    const int n   = blk & 31;
    const int t   = threadIdx.x;     // 256 threads
    const int f4  = t & 31;          // float4 column in unit dim (32 x float4 = 128 floats)
    const int sub = t >> 5;          // 8 i-subgroups

    // float4 units: batch stride = 1048576/4 = 262144; i stride = 4096/4 = 1024; n stride = 128/4 = 32
    const float4* __restrict__ xb =
        reinterpret_cast<const float4*>(x)
        + (size_t)b * 262144u + (size_t)n * 32u + (size_t)f4;

    float4 acc = make_float4(0.f, 0.f, 0.f, 0.f);
    #pragma unroll
    for (int k = 0; k < 32; ++k) {
        const int i = sub + (k << 3);            // i = sub, sub+8, ..., sub+248
        const float4 v = xb[(size_t)i * 1024u];
        acc.x += v.x; acc.y += v.y; acc.z += v.z; acc.w += v.w;
    }

    __shared__ float4 lds[8][32];
    lds[sub][f4] = acc;
    __syncthreads();

    if (t < 32) {
        float4 s = lds[0][t];
        #pragma unroll
        for (int j = 1; j < 8; ++j) {
            const float4 v = lds[j][t];
            s.x += v.x; s.y += v.y; s.z += v.z; s.w += v.w;
        }
        const float inv = 1.0f / (float)IN_CH;
        s.x *= inv; s.y *= inv; s.z *= inv; s.w *= inv;

        // mag_sq over the 128-float unit vector: reduce across lanes 0..31
        float psq = s.x*s.x + s.y*s.y + s.z*s.z + s.w*s.w;
        #pragma unroll
        for (int m = 1; m <= 16; m <<= 1)
            psq += __shfl_xor(psq, m);

        const float mag   = sqrtf(psq);
        const float scale = psq / (1.0f + psq) / (mag + 1e-5f);
        s.x *= scale; s.y *= scale; s.z *= scale; s.w *= scale;

        float4* o = reinterpret_cast<float4*>(out) + (size_t)blk * 32u + t;
        *o = s;
    }
}

extern "C" void kernel_launch(void* const* d_in, const int* in_sizes, int n_in,
                              void* d_out, int out_size, void* d_ws, size_t ws_size,
                              hipStream_t stream)
{
    const float* x = (const float*)d_in[0];
    float* out = (float*)d_out;
    capsule_squash_kernel<<<BATCH * NUM_UNITS, 256, 0, stream>>>(x, out);
}